// Round 9
// baseline (368.858 us; speedup 1.0000x reference)
//
#include <hip/hip_runtime.h>
#include <hip/hip_bf16.h>
#include <stdint.h>

// AWQ GEMM: out[2048,11008](f32) = x[2048,4096](f32,f16-valued) @ dequant4(...) + bias
// Round 9: occupancy fix. Round 8 was latency/barrier-bound (MfmaUtil 20, VALU 21,
// Occ 21: 96KB LDS -> 1 block/CU -> all waves barrier-locked in the same phase).
// Now BM=128 (LDS 64KB) -> 2 independent blocks/CU -> 4 waves/SIMD with
// cross-block MFMA||VALU overlap. Dequant + layouts identical to round 8.

constexpr int IN_F   = 4096;
constexpr int OUT_F  = 11008;
constexpr int PCOLS  = OUT_F / 8;   // 1376
constexpr int BM = 128, BN = 128, BK = 64;
constexpr int NKT    = IN_F / BK;   // 64
constexpr int NTILES = OUT_F / BN;  // 86
constexpr int ABYTES = BM * BK * 2; // 16384
constexpr int BBYTES = BN * BK * 2; // 16384
constexpr int BUFB   = ABYTES + BBYTES; // 32768

typedef _Float16 h2 __attribute__((ext_vector_type(2)));
typedef _Float16 h8 __attribute__((ext_vector_type(8)));
typedef float f32x4  __attribute__((ext_vector_type(4)));

__device__ __forceinline__ h2 pkh2(float a, float b) {
    return __builtin_bit_cast(h2, __builtin_amdgcn_cvt_pkrtz(a, b));
}
__device__ __forceinline__ unsigned int pk2(float a, float b) {
    return __builtin_bit_cast(unsigned int, __builtin_amdgcn_cvt_pkrtz(a, b));
}

__global__ __launch_bounds__(512, 4)
void awq_gemm_kernel(const float* __restrict__ X,
                     const int*   __restrict__ QW,
                     const int*   __restrict__ QZ,
                     const float* __restrict__ S,
                     const float* __restrict__ BIAS,
                     float*       __restrict__ O)
{
    // buf b at smem + b*32768:  A [128 rows][128B] then B [128 cols][128B]
    // A: k-octet o of row r at 16B slot o^(r&7)
    // B: k-octet o of col n at 16B slot o^(n&7)^((n>>3)&7)
    __shared__ alignas(16) unsigned char smem[2 * BUFB];  // 65536

    const int t    = threadIdx.x;
    const int lane = t & 63;
    const int w    = t >> 6;      // 0..7
    const int wm   = w >> 1;      // 0..3 (row block of 32)
    const int wn   = w & 1;       // 0..1 (col block of 64)
    const int l15 = lane & 15, l45 = lane >> 4, l7 = lane & 7, l3 = (lane >> 3) & 1;

    // XCD-bijective mapping: XCD x (=bid&7) owns mtiles {2x,2x+1}, sweeps ntiles.
    const int bid   = blockIdx.x;            // 0..1375 = 8*172
    const int idx   = bid >> 3;              // 0..171
    const int mtile = (bid & 7) * 2 + idx / NTILES;
    const int ntile = idx % NTILES;
    const int m0 = mtile * BM;
    const int n0 = ntile * BN;
    const int P0 = n0 >> 3;

    // ---- A staging: thread covers rows {t>>3, (t>>3)+64}, k-octet t&7 ----
    const int arow = t >> 3;              // 0..63
    const int aoct = t & 7;
    const int aphys = aoct ^ (arow & 7);  // +64 preserves row&7
    const float* Xb = X + (size_t)(m0 + arow) * IN_F + aoct * 8;

    float4 areg[2][2];
    auto load_A = [&](int kt) {
#pragma unroll
        for (int i = 0; i < 2; ++i) {
            const float* p = Xb + (size_t)i * 64 * IN_F + kt * BK;
            areg[i][0] = *(const float4*)(p);
            areg[i][1] = *(const float4*)(p + 4);
        }
    };
    auto write_A = [&](int buf) {
        unsigned char* ab = smem + buf * BUFB;
#pragma unroll
        for (int i = 0; i < 2; ++i) {
            uint4 v;
            v.x = pk2(areg[i][0].x, areg[i][0].y);
            v.y = pk2(areg[i][0].z, areg[i][0].w);
            v.z = pk2(areg[i][1].x, areg[i][1].y);
            v.w = pk2(areg[i][1].z, areg[i][1].w);
            *(uint4*)(ab + (i * 64 + arow) * 128 + aphys * 16) = v;
        }
    };

    // ---- B staging: thread covers packed col pcol = t&15, k-pair 2kd, 2kd+1 (kd = t>>4) ----
    const int pcol = t & 15;
    const int kd   = t >> 4;         // 0..31
    const int pc7  = pcol & 7;
    const int ob   = kd >> 2;        // k-octet
    const int sub  = (kd & 3) * 4;   // byte offset within 16B slot
    const int* qwb = QW + (size_t)(2 * kd) * PCOLS + P0 + pcol;
    const unsigned int* qzc = (const unsigned int*)QZ + P0 + pcol;
    const float* scol = S + n0 + pcol * 8;

    constexpr int SH[8]   = {0, 16, 4, 20, 8, 24, 12, 28}; // shift of logical nibble j
    constexpr int JLO[4]  = {0, 4, 1, 5};                  // low-nibble j of byte b

    h2 spk[8], zpk[8];
    unsigned int zraw_n; float4 sv0, sv1;
    unsigned int raw0, raw1;

    auto load_group = [&](int g) {
        zraw_n = qzc[(size_t)g * PCOLS];
        sv0 = *(const float4*)(scol + (size_t)g * OUT_F);
        sv1 = *(const float4*)(scol + (size_t)g * OUT_F + 4);
    };
    auto compute_group = [&]() {
        const float sf[8] = {sv0.x, sv0.y, sv0.z, sv0.w, sv1.x, sv1.y, sv1.z, sv1.w};
#pragma unroll
        for (int j = 0; j < 8; ++j) {
            float zb = 1024.0f + (float)((zraw_n >> SH[j]) & 15u);  // exact in f16
            spk[j] = pkh2(sf[j], sf[j]);
            zpk[j] = pkh2(zb, zb);
        }
    };
    auto load_raws = [&](int kt) {
        const size_t off = (size_t)kt * BK * PCOLS;
        raw0 = (unsigned int)qwb[off];
        raw1 = (unsigned int)qwb[off + PCOLS];
    };
    auto stage_B = [&](int buf) {
        unsigned char* bb = smem + buf * BUFB + ABYTES;
#pragma unroll
        for (int b = 0; b < 4; ++b) {
            const int jl = JLO[b], jh = jl + 2;
            // byte b of raw0 -> dst byte0, byte b of raw1 -> dst byte2 (others masked)
            unsigned int d  = __builtin_amdgcn_perm(raw1, raw0,
                                 (unsigned int)(((4 + b) << 16) | b));
            unsigned int lo = (d & 0x000F000Fu) | 0x64006400u;         // (1024+q) pair, j=jl
            unsigned int hi = ((d >> 4) & 0x000F000Fu) | 0x64006400u;  // j=jh
            // exact sub (both exact ints in f16), then single f16 rounding on mul
            h2 wl = (__builtin_bit_cast(h2, lo) - zpk[jl]) * spk[jl];
            h2 wh = (__builtin_bit_cast(h2, hi) - zpk[jh]) * spk[jh];
            const int nl = pcol * 8 + jl, nh = pcol * 8 + jh;
            *(unsigned int*)(bb + nl * 128 + ((ob ^ jl ^ pc7) * 16) + sub) =
                __builtin_bit_cast(unsigned int, wl);
            *(unsigned int*)(bb + nh * 128 + ((ob ^ jh ^ pc7) * 16) + sub) =
                __builtin_bit_cast(unsigned int, wh);
        }
    };

    f32x4 acc[2][4];
#pragma unroll
    for (int mi = 0; mi < 2; ++mi)
#pragma unroll
        for (int ni = 0; ni < 4; ++ni)
            acc[mi][ni] = f32x4{0.f, 0.f, 0.f, 0.f};

    auto compute_tile = [&](int buf) {
        const unsigned char* ab = smem + buf * BUFB;
        const unsigned char* bb = smem + buf * BUFB + ABYTES;
#pragma unroll
        for (int ks = 0; ks < 2; ++ks) {
            h8 a[2], bf[4];
#pragma unroll
            for (int mi = 0; mi < 2; ++mi) {
                int off = (wm * 32 + mi * 16 + l15) * 128
                        + (((ks * 4 + l45) ^ l7) * 16);          // row&7 == l7
                a[mi] = *(const h8*)(ab + off);
            }
#pragma unroll
            for (int ni = 0; ni < 4; ++ni) {
                int off = (wn * 64 + ni * 16 + l15) * 128
                        + ((((ks * 4 + l45) ^ l7 ^ l3) ^ (2 * ni)) * 16); // n&7==l7
                bf[ni] = *(const h8*)(bb + off);
            }
#pragma unroll
            for (int mi = 0; mi < 2; ++mi)
#pragma unroll
                for (int ni = 0; ni < 4; ++ni)
                    acc[mi][ni] = __builtin_amdgcn_mfma_f32_16x16x32_f16(
                        a[mi], bf[ni], acc[mi][ni], 0, 0, 0);
        }
    };

    // ---- prologue ----
    load_A(0);
    load_raws(0);
    load_group(0);
    compute_group();
    write_A(0);
    stage_B(0);
    __syncthreads();

    // ---- main loop: single barrier per iter, dbuf ----
#pragma unroll 2
    for (int kt = 0; kt < NKT; ++kt) {
        const int cur = kt & 1;
        if (kt + 1 < NKT) {
            load_A(kt + 1);                    // issue-early (T14)
            load_raws(kt + 1);
            if (((kt + 1) & 1) == 0) load_group((kt + 1) >> 1);
        }
        compute_tile(cur);
        if (kt + 1 < NKT) {
            if (((kt + 1) & 1) == 0) compute_group();
            write_A(cur ^ 1);
            stage_B(cur ^ 1);
        }
        __syncthreads();
    }

    // ---- epilogue: bias + f32 store (C/D: col=lane&15, row=(lane>>4)*4+reg) ----
    const int orow0 = m0 + wm * 32 + l45 * 4;
    const int ocol0 = n0 + wn * 64 + l15;
    float bv[4];
#pragma unroll
    for (int ni = 0; ni < 4; ++ni)
        bv[ni] = BIAS[ocol0 + ni * 16];
#pragma unroll
    for (int mi = 0; mi < 2; ++mi)
#pragma unroll
        for (int ni = 0; ni < 4; ++ni)
#pragma unroll
            for (int r = 0; r < 4; ++r) {
                int row = orow0 + mi * 16 + r;
                int col = ocol0 + ni * 16;
                O[(size_t)row * OUT_F + col] = acc[mi][ni][r] + bv[ni];
            }
}

extern "C" void kernel_launch(void* const* d_in, const int* in_sizes, int n_in,
                              void* d_out, int out_size, void* d_ws, size_t ws_size,
                              hipStream_t stream) {
    const float* X  = (const float*)d_in[0];
    const int*   QW = (const int*)d_in[1];
    const int*   QZ = (const int*)d_in[2];
    const float* S  = (const float*)d_in[3];
    const float* Bi = (const float*)d_in[4];
    float*       O  = (float*)d_out;

    dim3 grid(16 * NTILES);   // 1376
    dim3 block(512);
    awq_gemm_kernel<<<grid, block, 0, stream>>>(X, QW, QZ, S, Bi, O);
}

// Round 10
// 345.864 us; speedup vs baseline: 1.0665x; 1.0665x over previous
//
#include <hip/hip_runtime.h>
#include <hip/hip_bf16.h>
#include <stdint.h>

// AWQ GEMM: out[2048,11008](f32) = x[2048,4096](f32,f16-valued) @ dequant4(...) + bias
// Round 10: round-8 geometry (BM=256, 512 thr, 96KB LDS dbuf) + 4-phase interleaved
// schedule (T3/T5: per phase {ds_read frags || 1/4 staging -> s_barrier -> setprio ->
// 8 MFMA -> s_barrier}) + prefetch-distance-2 on global loads (double reg sets,
// statically indexed). r8/r9 showed 2-phase lockstep = 640 TF structural ceiling
// (MfmaUtil 20, VALU 21-28, both pipes idle on barrier+vmcnt stalls).

constexpr int IN_F   = 4096;
constexpr int OUT_F  = 11008;
constexpr int PCOLS  = OUT_F / 8;   // 1376
constexpr int BM = 256, BN = 128, BK = 64;
constexpr int NKT    = IN_F / BK;   // 64
constexpr int NTILES = OUT_F / BN;  // 86
constexpr int ABYTES = BM * BK * 2; // 32768
constexpr int BBYTES = BN * BK * 2; // 16384
constexpr int BUFB   = ABYTES + BBYTES; // 49152
constexpr int LDSTOT = 2 * BUFB;        // 98304

typedef _Float16 h2 __attribute__((ext_vector_type(2)));
typedef _Float16 h8 __attribute__((ext_vector_type(8)));
typedef float f32x4  __attribute__((ext_vector_type(4)));

__device__ __forceinline__ h2 pkh2(float a, float b) {
    return __builtin_bit_cast(h2, __builtin_amdgcn_cvt_pkrtz(a, b));
}
__device__ __forceinline__ unsigned int pk2(float a, float b) {
    return __builtin_bit_cast(unsigned int, __builtin_amdgcn_cvt_pkrtz(a, b));
}

__global__ __launch_bounds__(512, 2)
void awq_gemm_kernel(const float* __restrict__ X,
                     const int*   __restrict__ QW,
                     const int*   __restrict__ QZ,
                     const float* __restrict__ S,
                     const float* __restrict__ BIAS,
                     float*       __restrict__ O)
{
    // buf b at smem + b*49152:  A [256 rows][128B] then B [128 cols][128B]
    // A: k-octet o of row r at 16B slot o^(r&7)
    // B: k-octet o of col n at 16B slot o^(n&7)^((n>>3)&7)
    extern __shared__ unsigned char smem[];

    const int t    = threadIdx.x;
    const int lane = t & 63;
    const int w    = t >> 6;      // 0..7
    const int wm   = w >> 1;      // 0..3 (row block of 64)
    const int wn   = w & 1;       // 0..1 (col block of 64)
    const int l15 = lane & 15, l45 = lane >> 4, l7 = lane & 7, l3 = (lane >> 3) & 1;

    // XCD mapping: XCD x (= bid&7) owns mtile x; sweeps all 86 ntiles. 688 = 8*86.
    const int bid   = blockIdx.x;
    const int mtile = bid & 7;
    const int ntile = bid >> 3;
    const int m0 = mtile * BM;
    const int n0 = ntile * BN;
    const int P0 = n0 >> 3;

    // ---- A staging: thread covers rows (t>>3)+64i, k-octet t&7 ----
    const int arow = t >> 3;              // 0..63
    const int aoct = t & 7;
    const int aphys = aoct ^ (arow & 7);  // 64i preserves row&7
    const float* Xb = X + (size_t)(m0 + arow) * IN_F + aoct * 8;

    auto load_A_to = [&](float4 (&ar)[4][2], int kt) {
#pragma unroll
        for (int i = 0; i < 4; ++i) {
            const float* p = Xb + (size_t)i * 64 * IN_F + kt * BK;
            ar[i][0] = *(const float4*)(p);
            ar[i][1] = *(const float4*)(p + 4);
        }
    };
    auto write_A_chunk = [&](unsigned char* ab, const float4 (&ar)[4][2], int i) {
        uint4 v;
        v.x = pk2(ar[i][0].x, ar[i][0].y);
        v.y = pk2(ar[i][0].z, ar[i][0].w);
        v.z = pk2(ar[i][1].x, ar[i][1].y);
        v.w = pk2(ar[i][1].z, ar[i][1].w);
        *(uint4*)(ab + (i * 64 + arow) * 128 + aphys * 16) = v;
    };

    // ---- B staging: thread covers packed col pcol = t&15, k-pair 2kd, 2kd+1 (kd = t>>4) ----
    const int pcol = t & 15;
    const int kd   = t >> 4;         // 0..31
    const int pc7  = pcol & 7;
    const int ob   = kd >> 2;        // k-octet
    const int sub  = (kd & 3) * 4;   // byte offset within 16B slot
    const int* qwb = QW + (size_t)(2 * kd) * PCOLS + P0 + pcol;
    const unsigned int* qzc = (const unsigned int*)QZ + P0 + pcol;
    const float* scol = S + n0 + pcol * 8;

    constexpr int SH[8]  = {0, 16, 4, 20, 8, 24, 12, 28}; // shift of logical nibble j
    constexpr int JLO[4] = {0, 4, 1, 5};                  // low-nibble j of byte b

    h2 spk[8], zpk[8];
    unsigned int zraw_n; float4 sv0, sv1;

    auto load_group = [&](int g) {
        zraw_n = qzc[(size_t)g * PCOLS];
        sv0 = *(const float4*)(scol + (size_t)g * OUT_F);
        sv1 = *(const float4*)(scol + (size_t)g * OUT_F + 4);
    };
    auto compute_group = [&]() {
        const float sf[8] = {sv0.x, sv0.y, sv0.z, sv0.w, sv1.x, sv1.y, sv1.z, sv1.w};
#pragma unroll
        for (int j = 0; j < 8; ++j) {
            float zb = 1024.0f + (float)((zraw_n >> SH[j]) & 15u);  // exact in f16
            spk[j] = pkh2(sf[j], sf[j]);
            zpk[j] = pkh2(zb, zb);
        }
    };
    auto load_raws_to = [&](unsigned int (&rw)[2], int kt) {
        const size_t off = (size_t)kt * BK * PCOLS;
        rw[0] = (unsigned int)qwb[off];
        rw[1] = (unsigned int)qwb[off + PCOLS];
    };
    auto stage_B_chunk = [&](unsigned char* bb, const unsigned int (&rw)[2], int b) {
        const int jl = JLO[b], jh = jl + 2;
        unsigned int d  = __builtin_amdgcn_perm(rw[1], rw[0],
                             (unsigned int)(((4 + b) << 16) | b));
        unsigned int lo = (d & 0x000F000Fu) | 0x64006400u;         // (1024+q) pair, j=jl
        unsigned int hi = ((d >> 4) & 0x000F000Fu) | 0x64006400u;  // j=jh
        h2 wl = (__builtin_bit_cast(h2, lo) - zpk[jl]) * spk[jl];  // exact sub, 1 rounding
        h2 wh = (__builtin_bit_cast(h2, hi) - zpk[jh]) * spk[jh];
        const int nl = pcol * 8 + jl, nh = pcol * 8 + jh;
        *(unsigned int*)(bb + nl * 128 + ((ob ^ jl ^ pc7) * 16) + sub) =
            __builtin_bit_cast(unsigned int, wl);
        *(unsigned int*)(bb + nh * 128 + ((ob ^ jh ^ pc7) * 16) + sub) =
            __builtin_bit_cast(unsigned int, wh);
    };

    auto read_a = [&](const unsigned char* ab, int mi, int ks) -> h8 {
        int off = (wm * 64 + mi * 16 + l15) * 128 + (((ks * 4 + l45) ^ l7) * 16);
        return *(const h8*)(ab + off);
    };
    auto read_b = [&](const unsigned char* bb, int ni, int ks) -> h8 {
        int off = (wn * 64 + ni * 16 + l15) * 128
                + ((((ks * 4 + l45) ^ l7 ^ l3) ^ (2 * ni)) * 16);
        return *(const h8*)(bb + off);
    };

    f32x4 acc[4][4];
#pragma unroll
    for (int mi = 0; mi < 4; ++mi)
#pragma unroll
        for (int ni = 0; ni < 4; ++ni)
            acc[mi][ni] = f32x4{0.f, 0.f, 0.f, 0.f};

    float4 aregA[4][2], aregB[4][2];
    unsigned int rawA[2], rawB[2];

    // ---- prologue: kt=0 -> LDS buf0; kt=1 -> reg set B ----
    load_A_to(aregA, 0);
    load_raws_to(rawA, 0);
    load_group(0);
    compute_group();
    {
        unsigned char* ab0 = smem;
        unsigned char* bb0 = smem + ABYTES;
#pragma unroll
        for (int i = 0; i < 4; ++i) write_A_chunk(ab0, aregA, i);
#pragma unroll
        for (int b = 0; b < 4; ++b) stage_B_chunk(bb0, rawA, b);
    }
    load_A_to(aregB, 1);
    load_raws_to(rawB, 1);
    __syncthreads();

    // ---- one K-iteration, 4-phase interleave ----
    auto K_ITER = [&](int kt,
                      float4 (&arC)[4][2], unsigned int (&rwC)[2],   // consume: data for kt+1
                      float4 (&arI)[4][2], unsigned int (&rwI)[2],   // issue: loads for kt+2
                      bool ISSUE, bool STAGE, bool GRPI, bool GRPC) {
        const int cur = kt & 1;
        const unsigned char* abC = smem + cur * BUFB;
        const unsigned char* bbC = abC + ABYTES;
        unsigned char* abN = smem + (cur ^ 1) * BUFB;
        unsigned char* bbN = abN + ABYTES;

        h8 a0, a1, b0, b1, b2, b3;
        auto CL = [&](int mi0) {  // 8 MFMAs: rows mi0, mi0+1 x all ni
            acc[mi0][0] = __builtin_amdgcn_mfma_f32_16x16x32_f16(a0, b0, acc[mi0][0], 0, 0, 0);
            acc[mi0][1] = __builtin_amdgcn_mfma_f32_16x16x32_f16(a0, b1, acc[mi0][1], 0, 0, 0);
            acc[mi0][2] = __builtin_amdgcn_mfma_f32_16x16x32_f16(a0, b2, acc[mi0][2], 0, 0, 0);
            acc[mi0][3] = __builtin_amdgcn_mfma_f32_16x16x32_f16(a0, b3, acc[mi0][3], 0, 0, 0);
            acc[mi0+1][0] = __builtin_amdgcn_mfma_f32_16x16x32_f16(a1, b0, acc[mi0+1][0], 0, 0, 0);
            acc[mi0+1][1] = __builtin_amdgcn_mfma_f32_16x16x32_f16(a1, b1, acc[mi0+1][1], 0, 0, 0);
            acc[mi0+1][2] = __builtin_amdgcn_mfma_f32_16x16x32_f16(a1, b2, acc[mi0+1][2], 0, 0, 0);
            acc[mi0+1][3] = __builtin_amdgcn_mfma_f32_16x16x32_f16(a1, b3, acc[mi0+1][3], 0, 0, 0);
        };

        // ---- phase 0: ks=0, mi=0,1 ----
        if (ISSUE) { load_A_to(arI, kt + 2); load_raws_to(rwI, kt + 2); }
        if (GRPI)  load_group((kt + 2) >> 1);
        if (GRPC)  compute_group();          // new group consts BEFORE any stage chunk
        b0 = read_b(bbC, 0, 0); b1 = read_b(bbC, 1, 0);
        b2 = read_b(bbC, 2, 0); b3 = read_b(bbC, 3, 0);
        a0 = read_a(abC, 0, 0); a1 = read_a(abC, 1, 0);
        if (STAGE) { write_A_chunk(abN, arC, 0); stage_B_chunk(bbN, rwC, 0); }
        __builtin_amdgcn_s_barrier();
        __builtin_amdgcn_s_setprio(1); CL(0); __builtin_amdgcn_s_setprio(0);
        __builtin_amdgcn_s_barrier();

        // ---- phase 1: ks=0, mi=2,3 ----
        a0 = read_a(abC, 2, 0); a1 = read_a(abC, 3, 0);
        if (STAGE) { write_A_chunk(abN, arC, 1); stage_B_chunk(bbN, rwC, 1); }
        __builtin_amdgcn_s_barrier();
        __builtin_amdgcn_s_setprio(1); CL(2); __builtin_amdgcn_s_setprio(0);
        __builtin_amdgcn_s_barrier();

        // ---- phase 2: ks=1, mi=0,1 ----
        b0 = read_b(bbC, 0, 1); b1 = read_b(bbC, 1, 1);
        b2 = read_b(bbC, 2, 1); b3 = read_b(bbC, 3, 1);
        a0 = read_a(abC, 0, 1); a1 = read_a(abC, 1, 1);
        if (STAGE) { write_A_chunk(abN, arC, 2); stage_B_chunk(bbN, rwC, 2); }
        __builtin_amdgcn_s_barrier();
        __builtin_amdgcn_s_setprio(1); CL(0); __builtin_amdgcn_s_setprio(0);
        __builtin_amdgcn_s_barrier();

        // ---- phase 3: ks=1, mi=2,3 ----
        a0 = read_a(abC, 2, 1); a1 = read_a(abC, 3, 1);
        if (STAGE) { write_A_chunk(abN, arC, 3); stage_B_chunk(bbN, rwC, 3); }
        __builtin_amdgcn_s_barrier();
        __builtin_amdgcn_s_setprio(1); CL(2); __builtin_amdgcn_s_setprio(0);
        __syncthreads();   // buffer flip (also closes phase 3)
    };

    // ---- main loop: prefetch distance 2, static reg-set alternation ----
#pragma unroll 1
    for (int kt = 0; kt < NKT - 2; kt += 2) {
        K_ITER(kt,     aregB, rawB, aregA, rawA, true,  true,  true,  false);
        K_ITER(kt + 1, aregA, rawA, aregB, rawB, true,  true,  false, true);
    }
    K_ITER(NKT - 2, aregB, rawB, aregA, rawA, false, true,  false, false);
    K_ITER(NKT - 1, aregA, rawA, aregB, rawB, false, false, false, false);

    // ---- epilogue: bias + f32 store (C/D: col=lane&15, row=(lane>>4)*4+reg) ----
    const int orow0 = m0 + wm * 64 + l45 * 4;
    const int ocol0 = n0 + wn * 64 + l15;
    float bv[4];
#pragma unroll
    for (int ni = 0; ni < 4; ++ni)
        bv[ni] = BIAS[ocol0 + ni * 16];
#pragma unroll
    for (int mi = 0; mi < 4; ++mi)
#pragma unroll
        for (int ni = 0; ni < 4; ++ni)
#pragma unroll
            for (int r = 0; r < 4; ++r) {
                int row = orow0 + mi * 16 + r;
                int col = ocol0 + ni * 16;
                O[(size_t)row * OUT_F + col] = acc[mi][ni][r] + bv[ni];
            }
}

extern "C" void kernel_launch(void* const* d_in, const int* in_sizes, int n_in,
                              void* d_out, int out_size, void* d_ws, size_t ws_size,
                              hipStream_t stream) {
    const float* X  = (const float*)d_in[0];
    const int*   QW = (const int*)d_in[1];
    const int*   QZ = (const int*)d_in[2];
    const float* S  = (const float*)d_in[3];
    const float* Bi = (const float*)d_in[4];
    float*       O  = (float*)d_out;

    dim3 grid(8 * NTILES);   // 688
    dim3 block(512);
    awq_gemm_kernel<<<grid, block, LDSTOT, stream>>>(X, QW, QZ, S, Bi, O);
}